// Round 6
// baseline (474.364 us; speedup 1.0000x reference)
//
#include <hip/hip_runtime.h>
#include <hip/hip_bf16.h>

// MultiHeadedAttention2: dual-stream MHA with elementwise-max merge of the two
// softmax attention maps. Inputs fp32 (detected & converted to bf16 in ws);
// internal compute bf16 MFMA; OUTPUT WRITTEN AS FP32 (reference output dtype).
//
// Pipeline (4 dispatches):
//  0) convert_inputs: dtype-probe + convert/copy to bf16 in ws.
//  1) qkv_gemm : 6 projections. Q,K -> [B,H,S,64] bf16, V -> [B,H,64,S] bf16.
//                XCD-chunked 1-D grid (m-major per chunk) for L2 locality.
//  2) attn_merged v3: KEY-SPLIT decomposition (R5 algorithm, spill-fixed).
//                Wave owns 16 keys of each 64-key tile; K/V read DIRECT
//                global->VGPR (L2-resident). Swapped QK (mfma(K,Q)) leaves P
//                in registers in exactly the PV A-fragment layout.
//                *** O accumulators live in AGPRs ("+a" asm constraint) ***
//                -> arch-VGPR demand ~120 + 128 AGPR = fits 256/wave budget,
//                no scratch spill (R5: "+v" forced 230+ arch VGPRs -> 128-reg
//                alloc + spills -> 305MB scratch writes, 2.4x slowdown).
//  3) out_gemm : output projections + bias -> d_out (FP32), XCD-chunked grid.

typedef unsigned short u16;
typedef __attribute__((ext_vector_type(8))) short short8;   // 8 x bf16 (4 VGPRs)
typedef __attribute__((ext_vector_type(4))) short s4pack;   // 4 x bf16 (8 B)
typedef __attribute__((ext_vector_type(4))) float floatx4;  // MFMA accumulator

#define B_DIM 8
#define S_DIM 1024
#define H_DIM 8
#define DK 64
#define DMODEL 512
#define NTOK (B_DIM * S_DIM)                 // 8192 tokens
#define SEG ((size_t)NTOK * DMODEL)          // 4194304 elems per tensor
#define WSEG ((size_t)DMODEL * DMODEL)       // 262144 elems per weight

#define SCHED_FENCE() __builtin_amdgcn_sched_barrier(0)
#define VMCNT0() asm volatile("s_waitcnt vmcnt(0)" ::: "memory")
#define BARRIER() __builtin_amdgcn_s_barrier()

__device__ __forceinline__ floatx4 mfma_bf16(short8 a, short8 b, floatx4 c) {
  return __builtin_amdgcn_mfma_f32_16x16x32_bf16(a, b, c, 0, 0, 0);
}

// 16x16x16 bf16 MFMA via inline asm, accumulator in AGPR (canonical ISA form:
// v_mfma_f32_16x16x16_bf16 a[0:3], v[0:1], v[2:3], a[0:3]). Keeping C/D in
// the AGPR class removes 128 arch-VGPRs of pressure (the R5 spill fix).
// MFMA->MFMA same-D accumulate chains are HW-safe; MFMA->accvgpr_read in the
// epilogue is guarded by explicit s_nops (compiler can't see asm latency).
__device__ __forceinline__ void mfma16(floatx4& c, s4pack a, s4pack b) {
  asm volatile("v_mfma_f32_16x16x16_bf16 %0, %1, %2, %0"
               : "+a"(c) : "v"(a), "v"(b));
}

__device__ __forceinline__ u16 f32_to_bf16_rne(float f) {
  unsigned u = __float_as_uint(f);
  unsigned r = u + 0x7FFFu + ((u >> 16) & 1u);
  return (u16)(r >> 16);
}

__device__ __forceinline__ float bf16_bits_to_f32(u16 u) {
  return __uint_as_float(((unsigned)u) << 16);
}

// async global->LDS, 16B per lane; lds is the wave-uniform base
// (HW deposits lane i at lds + i*16).
__device__ __forceinline__ void async_cp16(const u16* g, u16* lds) {
  __builtin_amdgcn_global_load_lds(
      (__attribute__((address_space(1))) void*)(const_cast<u16*>(g)),
      (__attribute__((address_space(3))) void*)(lds), 16, 0, 0);
}

// ---------------------------------------------------------------------------
// Kernel 0: dtype-detect + convert to bf16.
// ---------------------------------------------------------------------------
#define NT_CONV 18
struct ConvParams {
  const void* src[NT_CONV];
  u16* dst[NT_CONV];
  int n[NT_CONV];
  int coff[NT_CONV + 1];   // prefix sums of chunk counts
};

__global__ __launch_bounds__(256) void convert_inputs(ConvParams p) {
  __shared__ int flag_f32;
  const int blk = blockIdx.x;
  int t = 0;
  while (t + 1 < NT_CONV && blk >= p.coff[t + 1]) ++t;
  const int lc = blk - p.coff[t];
  const int n = p.n[t];
  const int tid = threadIdx.x;

  if (tid < 64) {
    const u16* s = (const u16*)p.src[t];
    int bad = 0;
#pragma unroll
    for (int j = 0; j < 8; ++j) {
      float f = bf16_bits_to_f32(s[tid * 8 + j]);
      bad |= !(fabsf(f) < 1e4f);   // catches huge AND NaN
    }
    bad |= __shfl_xor(bad, 1);
    bad |= __shfl_xor(bad, 2);
    bad |= __shfl_xor(bad, 4);
    bad |= __shfl_xor(bad, 8);
    bad |= __shfl_xor(bad, 16);
    bad |= __shfl_xor(bad, 32);
    if (tid == 0) flag_f32 = bad;
  }
  __syncthreads();
  const int is_f32 = flag_f32;
  const int base = lc * 65536;

  for (int it = 0; it < 32; ++it) {
    const int idx = base + (it * 256 + tid) * 8;
    if (idx + 8 > n) break;
    if (!is_f32) {
      *(short8*)&p.dst[t][idx] = *(const short8*)&((const u16*)p.src[t])[idx];
    } else {
      const float* s = (const float*)p.src[t] + idx;
      short8 o;
#pragma unroll
      for (int j = 0; j < 8; ++j) o[j] = (short)f32_to_bf16_rne(s[j]);
      *(short8*)&p.dst[t][idx] = o;
    }
  }
}

// ---------------------------------------------------------------------------
// 128x128 NT GEMM mainloop, 2-phase LDS double-buffer.
// ---------------------------------------------------------------------------
__device__ __forceinline__ void gemm128_mainloop(
    const u16* __restrict__ A, const u16* __restrict__ W,
    int m0, int n0, int K, u16* ldsA, u16* ldsB, floatx4 acc[4][4]) {
  const int tid = threadIdx.x;
  const int lane = tid & 63;
  const int wid = tid >> 6;
  const int wm = wid >> 1, wn = wid & 1;
  const int r = lane & 15, g = lane >> 4;

  const int stg_row = wid * 32 + (lane >> 2);
  const int stg_col = (lane & 3) * 8;

  const u16* ga0 = A + (size_t)(m0 + stg_row) * K + stg_col;
  const u16* ga1 = A + (size_t)(m0 + stg_row + 16) * K + stg_col;
  const u16* gb0 = W + (size_t)(n0 + stg_row) * K + stg_col;
  const u16* gb1 = W + (size_t)(n0 + stg_row + 16) * K + stg_col;
  const int lo0 = (wid * 32) * 32;        // wave-uniform LDS offsets
  const int lo1 = (wid * 32 + 16) * 32;

  // prologue: stage k0=0 into buffer 0
  async_cp16(ga0, ldsA + lo0);
  async_cp16(ga1, ldsA + lo1);
  async_cp16(gb0, ldsB + lo0);
  async_cp16(gb1, ldsB + lo1);
  VMCNT0();
  BARRIER();

  int cur = 0;
  for (int k0 = 0; k0 < K; k0 += 32) {
    const int nxt = cur ^ 1;
    const bool more = (k0 + 32 < K);
    if (more) {            // issue next tile early; buf nxt was freed by the
      const int nb = nxt * 4096;          // barrier at the end of last iter
      async_cp16(ga0 + k0 + 32, ldsA + nb + lo0);
      async_cp16(ga1 + k0 + 32, ldsA + nb + lo1);
      async_cp16(gb0 + k0 + 32, ldsB + nb + lo0);
      async_cp16(gb1 + k0 + 32, ldsB + nb + lo1);
    }
    const int cb = cur * 4096;
    short8 a[4], b[4];
#pragma unroll
    for (int i = 0; i < 4; ++i)
      a[i] = *(const short8*)&ldsA[cb + (wm * 64 + i * 16 + r) * 32 + g * 8];
#pragma unroll
    for (int j = 0; j < 4; ++j)
      b[j] = *(const short8*)&ldsB[cb + (wn * 64 + j * 16 + r) * 32 + g * 8];
#pragma unroll
    for (int i = 0; i < 4; ++i)
#pragma unroll
      for (int j = 0; j < 4; ++j)
        acc[i][j] = mfma_bf16(a[i], b[j], acc[i][j]);
    if (more) {
      SCHED_FENCE(); VMCNT0(); BARRIER(); SCHED_FENCE();
      cur = nxt;
    }
  }
}

// ---------------------------------------------------------------------------
// Kernel 1: QKV projections. 1-D grid = 1536, XCD-chunked, m-major per chunk.
// ---------------------------------------------------------------------------
struct QkvParams {
  const u16* X[2];
  const u16* W[2][3];
  const u16* Bias[2][3];
  u16* Out[2][3];
};

__global__ __launch_bounds__(256) void qkv_gemm(QkvParams p) {
  __shared__ u16 ldsA[2 * 128 * 32];
  __shared__ u16 ldsB[2 * 128 * 32];
  const int lin = blockIdx.x;
  const int wg = (lin & 7) * 192 + (lin >> 3);   // bijective (1536 = 8*192)
  const int m0 = (wg / 24) * 128;
  const int c = wg % 24;
  const int z = c / 12;
  const int yc = c % 12;
  const int wi = yc >> 2;                        // 0=Q 1=K 2=V
  const int n0 = (yc & 3) * 128;

  floatx4 acc[4][4];
  const floatx4 z4 = {0.f, 0.f, 0.f, 0.f};
#pragma unroll
  for (int i = 0; i < 4; ++i)
#pragma unroll
    for (int j = 0; j < 4; ++j) acc[i][j] = z4;

  gemm128_mainloop(p.X[z], p.W[z][wi], m0, n0, DMODEL, ldsA, ldsB, acc);

  const int tid = threadIdx.x, lane = tid & 63, wid = tid >> 6;
  const int wm = wid >> 1, wn = wid & 1, r = lane & 15, g = lane >> 4;
  const u16* bias = p.Bias[z][wi];
  u16* out = p.Out[z][wi];
  const float qscale = 0.125f * 1.4426950408889634f;  // 1/sqrt(dk) * log2(e)

#pragma unroll
  for (int j = 0; j < 4; ++j) {
    const int cc = n0 + wn * 64 + j * 16 + r;         // output col in [0,512)
    const float bv = bf16_bits_to_f32(bias[cc]);
    const int h = cc >> 6, d = cc & 63;
#pragma unroll
    for (int i = 0; i < 4; ++i) {
      const int row0 = m0 + wm * 64 + i * 16 + g * 4; // 4 consecutive tokens
      const int bb = row0 >> 10, ss0 = row0 & 1023;
      if (wi == 2) {
        // V^T: [B,H,64,S]. 4 consecutive ss at fixed d -> one 8B store.
        s4pack pk;
#pragma unroll
        for (int ii = 0; ii < 4; ++ii)
          pk[ii] = (short)f32_to_bf16_rne(acc[i][j][ii] + bv);
        *(s4pack*)&out[(((size_t)(bb * H_DIM + h)) * DK + d) * S_DIM + ss0] = pk;
      } else {
#pragma unroll
        for (int ii = 0; ii < 4; ++ii) {
          float v = acc[i][j][ii] + bv;
          if (wi == 0) v *= qscale;                   // Q: pre-scaled
          out[(((size_t)(bb * H_DIM + h)) * S_DIM + (ss0 + ii)) * DK + d] =
              f32_to_bf16_rne(v);
        }
      }
    }
  }
}

// ---------------------------------------------------------------------------
// Kernel 2 v3: merged-softmax attention, key-split, direct-global, AGPR-acc.
// grid = 1024 (64 bh x 16 q-tiles of QB=64), XCD-chunked swizzle.
//
// Wave w owns keys [kt*64 + w*16, +16) for every key-tile kt (16 tiles).
// Swapped QK: D = mfma(A=K-frag, B=Q-frag) -> D[m=key][n=q]:
//   lane(r,g): q = q0 + mt*16 + r (col), key = kbase + g*4 + i (row).
// This IS the 16x16x16 PV A-fragment layout: A[m=q=r][k=g*4+j] -> P stays in
// registers. O accumulated per-wave (AGPRs) over its keys; cross-wave reduce.
// ---------------------------------------------------------------------------
#define QB 64

struct AttnParams {
  const u16* Q[2];
  const u16* K[2];
  const u16* Vt[2];
  u16* O[2];
};

__global__ __launch_bounds__(256, 2) void attn_merged(AttnParams p) {
  __shared__ float ored[2][2][QB][DK];   // [pair-buf][s][q][d] = 64 KB
  __shared__ float sred[2][4][16][4];    // [s][mt][r][wave]    = 2 KB

  const int tid = threadIdx.x;
  const int lane = tid & 63;
  const int wid = tid >> 6;
  const int r = lane & 15, g = lane >> 4;

  // XCD-chunked bijective swizzle (1024 = 8 XCD * 128): each XCD gets 128
  // consecutive work items = 8 whole heads -> K/V working set L2-resident.
  const int lin = blockIdx.x;
  const int w = (lin & 7) * 128 + (lin >> 3);
  const int bh = w >> 4;                 // (b*8+h)
  const int q0 = (w & 15) * QB;          // q-tile base
  const size_t hbase = (size_t)bh * S_DIM * DK;

  const u16* __restrict__ Kp0 = p.K[0] + hbase;
  const u16* __restrict__ Kp1 = p.K[1] + hbase;
  const u16* __restrict__ Vp0 = p.Vt[0] + hbase;
  const u16* __restrict__ Vp1 = p.Vt[1] + hbase;

  // Q fragments (B-operand): lane holds Q[q=q0+mt*16+r][d=kc*32+g*8+j]
  short8 qf[2][4][2];
#pragma unroll
  for (int s = 0; s < 2; ++s)
#pragma unroll
    for (int mt = 0; mt < 4; ++mt)
#pragma unroll
      for (int kc = 0; kc < 2; ++kc)
        qf[s][mt][kc] = *(const short8*)
            &p.Q[s][hbase + (size_t)(q0 + mt * 16 + r) * DK + kc * 32 + g * 8];

  // K A-frag per-lane offset: K[key = kbase + r][d = kc*32 + g*8 ..]
  const int koff = (wid * 16 + r) * DK + g * 8;   // + kc*32 + kt*64*DK
  const floatx4 z4 = {0.f, 0.f, 0.f, 0.f};

  // ---- pass 1: per-q sums of 2^score over this wave's keys, both streams ----
  short8 kA[2][2];
  kA[0][0] = *(const short8*)&Kp0[koff];
  kA[0][1] = *(const short8*)&Kp0[koff + 32];
  kA[1][0] = *(const short8*)&Kp1[koff];
  kA[1][1] = *(const short8*)&Kp1[koff + 32];

  float sl[2][4];
#pragma unroll
  for (int s = 0; s < 2; ++s)
#pragma unroll
    for (int mt = 0; mt < 4; ++mt) sl[s][mt] = 0.f;

  for (int kt = 0; kt < 16; ++kt) {
#pragma unroll
    for (int mt = 0; mt < 4; ++mt) {
      floatx4 ar = mfma_bf16(kA[0][0], qf[0][mt][0], z4);
      ar = mfma_bf16(kA[0][1], qf[0][mt][1], ar);
      floatx4 af = mfma_bf16(kA[1][0], qf[1][mt][0], z4);
      af = mfma_bf16(kA[1][1], qf[1][mt][1], af);
      sl[0][mt] += __builtin_amdgcn_exp2f(ar[0]) + __builtin_amdgcn_exp2f(ar[1]) +
                   __builtin_amdgcn_exp2f(ar[2]) + __builtin_amdgcn_exp2f(ar[3]);
      sl[1][mt] += __builtin_amdgcn_exp2f(af[0]) + __builtin_amdgcn_exp2f(af[1]) +
                   __builtin_amdgcn_exp2f(af[2]) + __builtin_amdgcn_exp2f(af[3]);
    }
    if (kt < 15) {                       // reload kA for next tile (reg reuse)
      const int kn = (kt + 1) * 64 * DK + koff;
      kA[0][0] = *(const short8*)&Kp0[kn];
      kA[0][1] = *(const short8*)&Kp0[kn + 32];
      kA[1][0] = *(const short8*)&Kp1[kn];
      kA[1][1] = *(const short8*)&Kp1[kn + 32];
    }
  }

  // reduce over g (keys within wave), publish per-wave partials, combine.
#pragma unroll
  for (int s = 0; s < 2; ++s)
#pragma unroll
    for (int mt = 0; mt < 4; ++mt) {
      float v = sl[s][mt];
      v += __shfl_xor(v, 16);
      v += __shfl_xor(v, 32);
      if (g == 0) sred[s][mt][r][wid] = v;
    }
  __syncthreads();

  // prefetch pass-2 tile-0 K while computing inv
  kA[0][0] = *(const short8*)&Kp0[koff];
  kA[0][1] = *(const short8*)&Kp0[koff + 32];
  kA[1][0] = *(const short8*)&Kp1[koff];
  kA[1][1] = *(const short8*)&Kp1[koff + 32];

  float inv_[2][4];
#pragma unroll
  for (int s = 0; s < 2; ++s)
#pragma unroll
    for (int mt = 0; mt < 4; ++mt) {
      const floatx4 sv = *(const floatx4*)&sred[s][mt][r][0];
      inv_[s][mt] = 1.0f / (sv[0] + sv[1] + sv[2] + sv[3]);
    }

  floatx4 o_[2][4][4];   // [s][mt(q)][nt(d)] — lives in AGPRs via mfma16 "+a"
#pragma unroll
  for (int s = 0; s < 2; ++s)
#pragma unroll
    for (int mt = 0; mt < 4; ++mt)
#pragma unroll
      for (int nt = 0; nt < 4; ++nt) o_[s][mt][nt] = z4;

  // V B-frag per-lane offset: V^T[d = nt*16+r][key = kbase + g*4 ..]
  const int voff = r * S_DIM + wid * 16 + g * 4;   // + nt*16*S_DIM + kt*64

  // ---- pass 2: recompute scores, p = max(softmax_r, softmax_f), O += P@V ----
  for (int kt = 0; kt < 16; ++kt) {
    // V loads for THIS tile: consumed ~400cy later (after QK+softmax)
    s4pack vB[2][4];
#pragma unroll
    for (int nt = 0; nt < 4; ++nt) {
      const int va = voff + nt * 16 * S_DIM + kt * 64;
      vB[0][nt] = *(const s4pack*)&Vp0[va];
      vB[1][nt] = *(const s4pack*)&Vp1[va];
    }

    s4pack pA[4];
#pragma unroll
    for (int mt = 0; mt < 4; ++mt) {
      floatx4 ar = mfma_bf16(kA[0][0], qf[0][mt][0], z4);
      ar = mfma_bf16(kA[0][1], qf[0][mt][1], ar);
      floatx4 af = mfma_bf16(kA[1][0], qf[1][mt][0], z4);
      af = mfma_bf16(kA[1][1], qf[1][mt][1], af);
#pragma unroll
      for (int i = 0; i < 4; ++i) {
        const float pr = __builtin_amdgcn_exp2f(ar[i]) * inv_[0][mt];
        const float pf = __builtin_amdgcn_exp2f(af[i]) * inv_[1][mt];
        pA[mt][i] = (short)f32_to_bf16_rne(fmaxf(pr, pf));
      }
    }

    if (kt < 15) {                       // reload kA for next tile
      const int kn = (kt + 1) * 64 * DK + koff;
      kA[0][0] = *(const short8*)&Kp0[kn];
      kA[0][1] = *(const short8*)&Kp0[kn + 32];
      kA[1][0] = *(const short8*)&Kp1[kn];
      kA[1][1] = *(const short8*)&Kp1[kn + 32];
    }

    asm volatile("s_nop 7" :::);         // VALU(pA)->MFMA-read hazard guard
#pragma unroll
    for (int mt = 0; mt < 4; ++mt)
#pragma unroll
      for (int nt = 0; nt < 4; ++nt) {
        mfma16(o_[0][mt][nt], pA[mt], vB[0][nt]);
        mfma16(o_[1][mt][nt], pA[mt], vB[1][nt]);
      }
  }

  // MFMA(AGPR write) -> v_accvgpr_read hazard guard (asm latency invisible
  // to the compiler's hazard pass).
  asm volatile("s_nop 7\n\ts_nop 7" :::);

  // ---- cross-wave O reduction (two-stage, 64KB buffer) ----
  // lane(r,g) holds O_s[q = mt*16 + g*4 + i][d = nt*16 + r]
  if (wid < 2) {
#pragma unroll
    for (int s = 0; s < 2; ++s)
#pragma unroll
      for (int mt = 0; mt < 4; ++mt)
#pragma unroll
        for (int nt = 0; nt < 4; ++nt)
#pragma unroll
          for (int i = 0; i < 4; ++i)
            ored[wid][s][mt * 16 + g * 4 + i][nt * 16 + r] = o_[s][mt][nt][i];
  }
  __syncthreads();
  if (wid >= 2) {
#pragma unroll
    for (int s = 0; s < 2; ++s)
#pragma unroll
      for (int mt = 0; mt < 4; ++mt)
#pragma unroll
        for (int nt = 0; nt < 4; ++nt)
#pragma unroll
          for (int i = 0; i < 4; ++i)
            ored[wid - 2][s][mt * 16 + g * 4 + i][nt * 16 + r] += o_[s][mt][nt][i];
  }
  __syncthreads();

  // final: thread t handles (q = t>>2, d-segment (t&3)*16), both streams.
  const int q = tid >> 2, ds0 = (tid & 3) * 16;
  const int bb = bh >> 3, h = bh & 7;
#pragma unroll
  for (int s = 0; s < 2; ++s) {
    floatx4 v0 = *(const floatx4*)&ored[0][s][q][ds0 + 0];
    floatx4 v1 = *(const floatx4*)&ored[0][s][q][ds0 + 4];
    floatx4 v2 = *(const floatx4*)&ored[0][s][q][ds0 + 8];
    floatx4 v3 = *(const floatx4*)&ored[0][s][q][ds0 + 12];
    v0 += *(const floatx4*)&ored[1][s][q][ds0 + 0];
    v1 += *(const floatx4*)&ored[1][s][q][ds0 + 4];
    v2 += *(const floatx4*)&ored[1][s][q][ds0 + 8];
    v3 += *(const floatx4*)&ored[1][s][q][ds0 + 12];
    short8 lo, hi;
#pragma unroll
    for (int k = 0; k < 4; ++k) {
      lo[k] = (short)f32_to_bf16_rne(v0[k]);
      lo[4 + k] = (short)f32_to_bf16_rne(v1[k]);
      hi[k] = (short)f32_to_bf16_rne(v2[k]);
      hi[4 + k] = (short)f32_to_bf16_rne(v3[k]);
    }
    u16* out = p.O[s] + ((size_t)(bb * S_DIM + q0 + q)) * DMODEL + h * 64 + ds0;
    *(short8*)&out[0] = lo;
    *(short8*)&out[8] = hi;
  }
}

// ---------------------------------------------------------------------------
// Kernel 3: output projections. 1-D grid = 512, XCD-chunked, m-major.
// ---------------------------------------------------------------------------
struct OutParams {
  const u16* A[2];
  const u16* W[2];
  const u16* Bias[2];
  float* Out[2];
};

__global__ __launch_bounds__(256) void out_gemm(OutParams p) {
  __shared__ u16 ldsA[2 * 128 * 32];
  __shared__ u16 ldsB[2 * 128 * 32];
  const int lin = blockIdx.x;
  const int wg = (lin & 7) * 64 + (lin >> 3);   // bijective (512 = 8*64)
  const int m0 = (wg >> 3) * 128;
  const int c = wg & 7;
  const int z = c >> 2;
  const int n0 = (c & 3) * 128;

  floatx4 acc[4][4];
  const floatx4 z4 = {0.f, 0.f, 0.f, 0.f};
#pragma unroll
  for (int i = 0; i < 4; ++i)
#pragma unroll
    for (int j = 0; j < 4; ++j) acc[i][j] = z4;

  gemm128_mainloop(p.A[z], p.W[z], m0, n0, DMODEL, ldsA, ldsB, acc);

  const int tid = threadIdx.x, lane = tid & 63, wid = tid >> 6;
  const int wm = wid >> 1, wn = wid & 1, r = lane & 15, g = lane >> 4;
  const u16* bias = p.Bias[z];
  float* out = p.Out[z];

#pragma unroll
  for (int j = 0; j < 4; ++j) {
    const int cc = n0 + wn * 64 + j * 16 + r;
    const float bv = bf16_bits_to_f32(bias[cc]);
#pragma unroll
    for (int i = 0; i < 4; ++i) {
      const int row0 = m0 + wm * 64 + i * 16 + g * 4;
#pragma unroll
      for (int ii = 0; ii < 4; ++ii)
        out[(size_t)(row0 + ii) * DMODEL + cc] = acc[i][j][ii] + bv;   // FP32
    }
  }
}

// ---------------------------------------------------------------------------
extern "C" void kernel_launch(void* const* d_in, const int* in_sizes, int n_in,
                              void* d_out, int out_size, void* d_ws, size_t ws_size,
                              hipStream_t stream) {
  (void)in_sizes; (void)n_in; (void)out_size; (void)ws_size;
  u16* ws = (u16*)d_ws;
  u16* Qr = ws + 0 * SEG;
  u16* Kr = ws + 1 * SEG;
  u16* Vr = ws + 2 * SEG;   // stored transposed [B,H,64,S]
  u16* Qf = ws + 3 * SEG;
  u16* Kf = ws + 4 * SEG;
  u16* Vf = ws + 5 * SEG;   // stored transposed [B,H,64,S]
  u16* Or = ws + 6 * SEG;   // also holds converted X_rgb before attn overwrites
  u16* Of = ws + 7 * SEG;   // also holds converted X_flow
  u16* cW = ws + 8 * SEG;            // 8 x 262144
  u16* cB = cW + 8 * WSEG;           // 8 x 512

  // ---- conversion pre-pass ----
  ConvParams cp;
  int coff = 0;
  for (int i = 0; i < NT_CONV; ++i) {
    cp.src[i] = d_in[i];
    int n;
    if (i < 2) {
      n = (int)SEG;
      cp.dst[i] = (i == 0) ? Or : Of;
    } else {
      const int k = (i - 2) >> 1;
      const int isb = (i - 2) & 1;
      n = isb ? DMODEL : (int)WSEG;
      cp.dst[i] = isb ? (cB + k * DMODEL) : (cW + k * WSEG);
    }
    cp.n[i] = n;
    cp.coff[i] = coff;
    coff += (n + 65535) / 65536;
  }
  cp.coff[NT_CONV] = coff;   // 168 chunks total
  convert_inputs<<<dim3(coff), dim3(256), 0, stream>>>(cp);

  // ---- QKV projections ----
  QkvParams qp;
  qp.X[0] = Or;
  qp.X[1] = Of;
  for (int s = 0; s < 2; ++s)
    for (int wi = 0; wi < 3; ++wi) {
      const int k = s * 3 + wi;
      qp.W[s][wi] = cW + k * WSEG;
      qp.Bias[s][wi] = cB + k * DMODEL;
    }
  qp.Out[0][0] = Qr; qp.Out[0][1] = Kr; qp.Out[0][2] = Vr;
  qp.Out[1][0] = Qf; qp.Out[1][1] = Kf; qp.Out[1][2] = Vf;
  qkv_gemm<<<dim3(1536), dim3(256), 0, stream>>>(qp);

  // ---- merged attention (overwrites Or/Of with O) ----
  AttnParams ap;
  ap.Q[0] = Qr; ap.Q[1] = Qf;
  ap.K[0] = Kr; ap.K[1] = Kf;
  ap.Vt[0] = Vr; ap.Vt[1] = Vf;
  ap.O[0] = Or; ap.O[1] = Of;
  attn_merged<<<dim3(1024), dim3(256), 0, stream>>>(ap);

  // ---- output projections (fp32 out) ----
  OutParams op;
  op.A[0] = Or; op.A[1] = Of;
  op.W[0] = cW + 6 * WSEG; op.Bias[0] = cB + 6 * DMODEL;
  op.W[1] = cW + 7 * WSEG; op.Bias[1] = cB + 7 * DMODEL;
  op.Out[0] = (float*)d_out;
  op.Out[1] = (float*)d_out + SEG;
  out_gemm<<<dim3(512), dim3(256), 0, stream>>>(op);
}

// Round 7
// 284.754 us; speedup vs baseline: 1.6659x; 1.6659x over previous
//
#include <hip/hip_runtime.h>
#include <hip/hip_bf16.h>

// MultiHeadedAttention2: dual-stream MHA with elementwise-max merge of the two
// softmax attention maps. Inputs fp32 (detected & converted to bf16 in ws);
// internal compute bf16 MFMA; OUTPUT WRITTEN AS FP32 (reference output dtype).
//
// Pipeline (4 dispatches):
//  0) convert_inputs: dtype-probe + convert/copy to bf16 in ws.
//  1) qkv_gemm : 6 projections. Q,K -> [B,H,S,64] bf16, V -> [B,H,64,S] bf16.
//                XCD-chunked 1-D grid; 3-buffer counted-vmcnt mainloop.
//  2) attn_merged v4: R3's proven q-split + LDS-staged structure, but QK is
//                computed SWAPPED (mfma(A=K, B=Q) -> D[key][q=r]) so each
//                lane's P values land exactly in the 16x16x16 PV A-fragment:
//                P never touches LDS (R3's Ps round-trip + conflicts gone),
//                softmax reduce is 2 shfl_xor, inv is a per-lane scalar.
//                Register pressure stays R3-small (o_ = 8 floatx4) -> no
//                spill (the R5/R6 key-split failure mode).
//  3) out_gemm : output projections + bias -> d_out (FP32), XCD-chunked grid.

typedef unsigned short u16;
typedef __attribute__((ext_vector_type(8))) short short8;   // 8 x bf16 (4 VGPRs)
typedef __attribute__((ext_vector_type(4))) short s4pack;   // 4 x bf16 (8 B)
typedef __attribute__((ext_vector_type(4))) float floatx4;  // MFMA accumulator

#define B_DIM 8
#define S_DIM 1024
#define H_DIM 8
#define DK 64
#define DMODEL 512
#define NTOK (B_DIM * S_DIM)                 // 8192 tokens
#define SEG ((size_t)NTOK * DMODEL)          // 4194304 elems per tensor
#define WSEG ((size_t)DMODEL * DMODEL)       // 262144 elems per weight

#define SCHED_FENCE() __builtin_amdgcn_sched_barrier(0)
#define LGKM0() asm volatile("s_waitcnt lgkmcnt(0)" ::: "memory")
#define VMCNT0() asm volatile("s_waitcnt vmcnt(0)" ::: "memory")
#define BARRIER() __builtin_amdgcn_s_barrier()

__device__ __forceinline__ floatx4 mfma_bf16(short8 a, short8 b, floatx4 c) {
  return __builtin_amdgcn_mfma_f32_16x16x32_bf16(a, b, c, 0, 0, 0);
}

// 16x16x16 bf16 MFMA via inline asm (gfx950 ISA §10: A/B = 2 VGPRs = 4 bf16,
// C/D = 4 VGPRs). "+v" constraint: accumulator in arch VGPRs — fine here,
// attn v4 holds only 8 accumulators. Numerically verified in R5 (passed).
__device__ __forceinline__ void mfma16(floatx4& c, s4pack a, s4pack b) {
  asm volatile("v_mfma_f32_16x16x16_bf16 %0, %1, %2, %0"
               : "+v"(c) : "v"(a), "v"(b));
}

__device__ __forceinline__ u16 f32_to_bf16_rne(float f) {
  unsigned u = __float_as_uint(f);
  unsigned r = u + 0x7FFFu + ((u >> 16) & 1u);
  return (u16)(r >> 16);
}

__device__ __forceinline__ float bf16_bits_to_f32(u16 u) {
  return __uint_as_float(((unsigned)u) << 16);
}

// async global->LDS, 16B per lane; lds is the wave-uniform base
// (HW deposits lane i at lds + i*16).
__device__ __forceinline__ void async_cp16(const u16* g, u16* lds) {
  __builtin_amdgcn_global_load_lds(
      (__attribute__((address_space(1))) void*)(const_cast<u16*>(g)),
      (__attribute__((address_space(3))) void*)(lds), 16, 0, 0);
}

// ---------------------------------------------------------------------------
// Kernel 0: dtype-detect + convert to bf16.
// ---------------------------------------------------------------------------
#define NT_CONV 18
struct ConvParams {
  const void* src[NT_CONV];
  u16* dst[NT_CONV];
  int n[NT_CONV];
  int coff[NT_CONV + 1];   // prefix sums of chunk counts
};

__global__ __launch_bounds__(256) void convert_inputs(ConvParams p) {
  __shared__ int flag_f32;
  const int blk = blockIdx.x;
  int t = 0;
  while (t + 1 < NT_CONV && blk >= p.coff[t + 1]) ++t;
  const int lc = blk - p.coff[t];
  const int n = p.n[t];
  const int tid = threadIdx.x;

  if (tid < 64) {
    const u16* s = (const u16*)p.src[t];
    int bad = 0;
#pragma unroll
    for (int j = 0; j < 8; ++j) {
      float f = bf16_bits_to_f32(s[tid * 8 + j]);
      bad |= !(fabsf(f) < 1e4f);   // catches huge AND NaN
    }
    bad |= __shfl_xor(bad, 1);
    bad |= __shfl_xor(bad, 2);
    bad |= __shfl_xor(bad, 4);
    bad |= __shfl_xor(bad, 8);
    bad |= __shfl_xor(bad, 16);
    bad |= __shfl_xor(bad, 32);
    if (tid == 0) flag_f32 = bad;
  }
  __syncthreads();
  const int is_f32 = flag_f32;
  const int base = lc * 65536;

  for (int it = 0; it < 32; ++it) {
    const int idx = base + (it * 256 + tid) * 8;
    if (idx + 8 > n) break;
    if (!is_f32) {
      *(short8*)&p.dst[t][idx] = *(const short8*)&((const u16*)p.src[t])[idx];
    } else {
      const float* s = (const float*)p.src[t] + idx;
      short8 o;
#pragma unroll
      for (int j = 0; j < 8; ++j) o[j] = (short)f32_to_bf16_rne(s[j]);
      *(short8*)&p.dst[t][idx] = o;
    }
  }
}

// ---------------------------------------------------------------------------
// 128x128 NT GEMM mainloop, 3-buffer counted-vmcnt pipeline (T4).
// K = 512 fixed (16 tiles of BK=32). Per iter: wait vmcnt(8) (tile kt's 4
// loads done, issued 3 iters ago -> fully hidden), barrier, compute, barrier,
// re-issue tile kt+3 into the freed buffer. No vmcnt(0) drain in steady state.
// ldsA/ldsB are [3][128*32] u16 (24 KB each).
// ---------------------------------------------------------------------------
__device__ __forceinline__ void gemm128_mainloop(
    const u16* __restrict__ A, const u16* __restrict__ W,
    int m0, int n0, u16* ldsA, u16* ldsB, floatx4 acc[4][4]) {
  const int tid = threadIdx.x;
  const int lane = tid & 63;
  const int wid = tid >> 6;
  const int wm = wid >> 1, wn = wid & 1;
  const int r = lane & 15, g = lane >> 4;

  const int stg_row = wid * 32 + (lane >> 2);
  const int stg_col = (lane & 3) * 8;

  const u16* ga0 = A + (size_t)(m0 + stg_row) * DMODEL + stg_col;
  const u16* ga1 = A + (size_t)(m0 + stg_row + 16) * DMODEL + stg_col;
  const u16* gb0 = W + (size_t)(n0 + stg_row) * DMODEL + stg_col;
  const u16* gb1 = W + (size_t)(n0 + stg_row + 16) * DMODEL + stg_col;
  const int lo0 = (wid * 32) * 32;        // wave-uniform LDS offsets
  const int lo1 = (wid * 32 + 16) * 32;

  // prologue: tiles 0..2 -> bufs 0..2 (12 loads/wave in flight)
#pragma unroll
  for (int t = 0; t < 3; ++t) {
    const int nb = t * 4096;
    const int ko = t * 32;
    async_cp16(ga0 + ko, ldsA + nb + lo0);
    async_cp16(ga1 + ko, ldsA + nb + lo1);
    async_cp16(gb0 + ko, ldsB + nb + lo0);
    async_cp16(gb1 + ko, ldsB + nb + lo1);
  }

#pragma unroll
  for (int kt = 0; kt < 16; ++kt) {
    // wait for THIS wave's tile-kt loads (counted, never 0 in steady state);
    // barrier makes it all-waves.
    SCHED_FENCE();
    if (kt < 14)       asm volatile("s_waitcnt vmcnt(8)" ::: "memory");
    else if (kt == 14) asm volatile("s_waitcnt vmcnt(4)" ::: "memory");
    else               asm volatile("s_waitcnt vmcnt(0)" ::: "memory");
    BARRIER();
    SCHED_FENCE();

    const int cb = (kt % 3) * 4096;
    short8 a[4], b[4];
#pragma unroll
    for (int i = 0; i < 4; ++i)
      a[i] = *(const short8*)&ldsA[cb + (wm * 64 + i * 16 + r) * 32 + g * 8];
#pragma unroll
    for (int j = 0; j < 4; ++j)
      b[j] = *(const short8*)&ldsB[cb + (wn * 64 + j * 16 + r) * 32 + g * 8];
#pragma unroll
    for (int i = 0; i < 4; ++i)
#pragma unroll
      for (int j = 0; j < 4; ++j)
        acc[i][j] = mfma_bf16(a[i], b[j], acc[i][j]);

    if (kt + 3 < 16) {
      // all waves' reads of buf[kt%3] complete (lgkm waited before MFMAs);
      // safe to overwrite it with tile kt+3.
      SCHED_FENCE(); BARRIER(); SCHED_FENCE();
      const int ko = (kt + 3) * 32;
      async_cp16(ga0 + ko, ldsA + cb + lo0);
      async_cp16(ga1 + ko, ldsA + cb + lo1);
      async_cp16(gb0 + ko, ldsB + cb + lo0);
      async_cp16(gb1 + ko, ldsB + cb + lo1);
    }
  }
}

// ---------------------------------------------------------------------------
// Kernel 1: QKV projections. 1-D grid = 1536, XCD-chunked, m-major per chunk.
// ---------------------------------------------------------------------------
struct QkvParams {
  const u16* X[2];
  const u16* W[2][3];
  const u16* Bias[2][3];
  u16* Out[2][3];
};

__global__ __launch_bounds__(256) void qkv_gemm(QkvParams p) {
  __shared__ u16 ldsA[3 * 128 * 32];
  __shared__ u16 ldsB[3 * 128 * 32];
  const int lin = blockIdx.x;
  const int wg = (lin & 7) * 192 + (lin >> 3);   // bijective (1536 = 8*192)
  const int m0 = (wg / 24) * 128;
  const int c = wg % 24;
  const int z = c / 12;
  const int yc = c % 12;
  const int wi = yc >> 2;                        // 0=Q 1=K 2=V
  const int n0 = (yc & 3) * 128;

  floatx4 acc[4][4];
  const floatx4 z4 = {0.f, 0.f, 0.f, 0.f};
#pragma unroll
  for (int i = 0; i < 4; ++i)
#pragma unroll
    for (int j = 0; j < 4; ++j) acc[i][j] = z4;

  gemm128_mainloop(p.X[z], p.W[z][wi], m0, n0, ldsA, ldsB, acc);

  const int tid = threadIdx.x, lane = tid & 63, wid = tid >> 6;
  const int wm = wid >> 1, wn = wid & 1, r = lane & 15, g = lane >> 4;
  const u16* bias = p.Bias[z][wi];
  u16* out = p.Out[z][wi];
  const float qscale = 0.125f * 1.4426950408889634f;  // 1/sqrt(dk) * log2(e)

#pragma unroll
  for (int j = 0; j < 4; ++j) {
    const int cc = n0 + wn * 64 + j * 16 + r;         // output col in [0,512)
    const float bv = bf16_bits_to_f32(bias[cc]);
    const int h = cc >> 6, d = cc & 63;
#pragma unroll
    for (int i = 0; i < 4; ++i) {
      const int row0 = m0 + wm * 64 + i * 16 + g * 4; // 4 consecutive tokens
      const int bb = row0 >> 10, ss0 = row0 & 1023;
      if (wi == 2) {
        // V^T: [B,H,64,S]. 4 consecutive ss at fixed d -> one 8B store.
        s4pack pk;
#pragma unroll
        for (int ii = 0; ii < 4; ++ii)
          pk[ii] = (short)f32_to_bf16_rne(acc[i][j][ii] + bv);
        *(s4pack*)&out[(((size_t)(bb * H_DIM + h)) * DK + d) * S_DIM + ss0] = pk;
      } else {
#pragma unroll
        for (int ii = 0; ii < 4; ++ii) {
          float v = acc[i][j][ii] + bv;
          if (wi == 0) v *= qscale;                   // Q: pre-scaled
          out[(((size_t)(bb * H_DIM + h)) * S_DIM + (ss0 + ii)) * DK + d] =
              f32_to_bf16_rne(v);
        }
      }
    }
  }
}

// ---------------------------------------------------------------------------
// Kernel 2 v4: merged-softmax attention. grid = 1024, XCD-chunked swizzle.
// R3 structure: block = 64 q rows of one (b,h); wave w owns q rows
// [w*16, w*16+16); KVB=32; K/V staged in swizzled LDS via the T14 reg-staged
// raw-barrier pipeline (proven in R3: 89.3 us).
//
// NEW: swapped QK.  D = mfma(A=K, B=Q) -> D[m=key][n=q]: lane(r,g) holds
// q = q0+wid*16+r, keys kt2*16 + g*4+i. That IS the 16x16x16 PV A-fragment
// A[m=q=r][k=key=g*4+j] -> P stays in registers (no Ps LDS), the softmax
// row-sum is 2 shfl_xor over g, and inv is one scalar per stream per lane.
// PV: O[m=q g*4+i][n=d r] accumulated via mfma16 with V^T b64 B-frags.
// ---------------------------------------------------------------------------
#define KVB 32
#define QB 64

struct AttnParams {
  const u16* Q[2];
  const u16* K[2];
  const u16* Vt[2];
  u16* O[2];
};

__global__ __launch_bounds__(256, 3) void attn_merged(AttnParams p) {
  __shared__ u16 Ks[2][KVB * 64];   // [stream][key][d], chunk-swizzled
  __shared__ u16 Vs[2][64 * KVB];   // [stream][d][key], chunk-swizzled

  const int tid = threadIdx.x;
  const int lane = tid & 63;
  const int wid = tid >> 6;
  const int r = lane & 15, g = lane >> 4;

  // XCD-chunked bijective swizzle (1024 = 8 XCD * 128): each XCD gets 128
  // consecutive work items = 8 whole heads -> K/V working set L2-resident.
  const int lin = blockIdx.x;
  const int w = (lin & 7) * 128 + (lin >> 3);
  const int bh = w >> 4;                 // (b*8+h)
  const int q0 = (w & 15) * QB;          // q-tile base
  const size_t hbase = (size_t)bh * S_DIM * DK;

  // K staging: thread -> (krow in [0,32), chunk kch in [0,8)); LDS chunk
  // XOR-swizzled by krow (read with same XOR -> conflict-free, proven R3).
  const int krow = tid >> 3, kch = tid & 7;
  const int kdst = krow * 64 + ((kch ^ (krow & 7)) * 8);
  const size_t kgsrc = (size_t)krow * DK + kch * 8;
  // V staging: thread -> (vrow=d in [0,64), chunk vch in [0,4))
  const int vrow = tid >> 2, vch = tid & 3;
  const int vdst = vrow * KVB + ((vch ^ ((vrow >> 2) & 3)) * 8);
  const size_t vgsrc = (size_t)vrow * S_DIM + vch * 8;

  // Q fragments (B-operand now; same per-lane data as R3's A-layout):
  // lane holds Q[q=q0+wid*16+r][d=kc*32+g*8+j]
  short8 qf[2][2];
#pragma unroll
  for (int s = 0; s < 2; ++s)
#pragma unroll
    for (int kc = 0; kc < 2; ++kc)
      qf[s][kc] = *(const short8*)
          &p.Q[s][hbase + (size_t)(q0 + wid * 16 + r) * DK + kc * 32 + g * 8];

  // tile-0 K prefetch
  short8 kst[2], vst[2];
#pragma unroll
  for (int s = 0; s < 2; ++s)
    kst[s] = *(const short8*)&p.K[s][hbase + kgsrc];

  const floatx4 z4 = {0.f, 0.f, 0.f, 0.f};
  float sl[2] = {0.f, 0.f};   // sum of 2^score for q=r over this lane's keys

  // ---- pass 1: per-q sums of 2^score for both streams ----
  for (int kt = 0; kt < 32; ++kt) {
    if (kt) { SCHED_FENCE(); BARRIER(); SCHED_FENCE(); }
#pragma unroll
    for (int s = 0; s < 2; ++s)       // implicit counted vmcnt on kst only
      *(short8*)&Ks[s][kdst] = kst[s];
    if (kt < 31) {
      const size_t k0n = (size_t)(kt + 1) * KVB * DK;
#pragma unroll
      for (int s = 0; s < 2; ++s)
        kst[s] = *(const short8*)&p.K[s][hbase + k0n + kgsrc];
    }
    SCHED_FENCE(); LGKM0(); BARRIER(); SCHED_FENCE();

#pragma unroll
    for (int s = 0; s < 2; ++s)
#pragma unroll
      for (int kt2 = 0; kt2 < 2; ++kt2) {
        const int row = kt2 * 16 + r;
        const short8 kf0 = *(const short8*)&Ks[s][row * 64 + ((g ^ (r & 7)) * 8)];
        const short8 kf1 =
            *(const short8*)&Ks[s][row * 64 + (((4 + g) ^ (r & 7)) * 8)];
        floatx4 acc = mfma_bf16(kf0, qf[s][0], z4);     // SWAPPED: A=K, B=Q
        acc = mfma_bf16(kf1, qf[s][1], acc);
        sl[s] += __builtin_amdgcn_exp2f(acc[0]) + __builtin_amdgcn_exp2f(acc[1]) +
                 __builtin_amdgcn_exp2f(acc[2]) + __builtin_amdgcn_exp2f(acc[3]);
      }
  }

  // pass-2 tile-0 staged loads: issued now so they fly under the reduction
#pragma unroll
  for (int s = 0; s < 2; ++s) {
    kst[s] = *(const short8*)&p.K[s][hbase + kgsrc];
    vst[s] = *(const short8*)&p.Vt[s][hbase + vgsrc];
  }

  // reduce over g (key groups); lane keeps the total for its q=r.
  float inv_[2];
#pragma unroll
  for (int s = 0; s < 2; ++s) {
    float v = sl[s];
    v += __shfl_xor(v, 16);
    v += __shfl_xor(v, 32);
    inv_[s] = 1.0f / v;
  }

  floatx4 o_[2][4];   // [s][nt(d)] : lane holds O[q=g*4+i][d=nt*16+r]
#pragma unroll
  for (int s = 0; s < 2; ++s)
#pragma unroll
    for (int nt = 0; nt < 4; ++nt) o_[s][nt] = z4;

  // ---- pass 2: recompute scores, p = max(softmax_r, softmax_f), O += P@V ----
  for (int kt = 0; kt < 32; ++kt) {
    // kt==0 barrier also closes pass-1's last readers of Ks
    SCHED_FENCE(); BARRIER(); SCHED_FENCE();
#pragma unroll
    for (int s = 0; s < 2; ++s) {
      *(short8*)&Ks[s][kdst] = kst[s];
      *(short8*)&Vs[s][vdst] = vst[s];
    }
    if (kt < 31) {
      const size_t kn = (size_t)(kt + 1) * KVB;
#pragma unroll
      for (int s = 0; s < 2; ++s) {
        kst[s] = *(const short8*)&p.K[s][hbase + kn * DK + kgsrc];
        vst[s] = *(const short8*)&p.Vt[s][hbase + vgsrc + kn];
      }
    }
    SCHED_FENCE(); LGKM0(); BARRIER(); SCHED_FENCE();

    // QK (swapped) + merged softmax -> pA[kt2] = P[key kt2*16+g*4+i][q=r]
    s4pack pA[2];
#pragma unroll
    for (int kt2 = 0; kt2 < 2; ++kt2) {
      const int row = kt2 * 16 + r;
      const short8 br0 = *(const short8*)&Ks[0][row * 64 + ((g ^ (r & 7)) * 8)];
      const short8 br1 =
          *(const short8*)&Ks[0][row * 64 + (((4 + g) ^ (r & 7)) * 8)];
      const short8 bf0 = *(const short8*)&Ks[1][row * 64 + ((g ^ (r & 7)) * 8)];
      const short8 bf1 =
          *(const short8*)&Ks[1][row * 64 + (((4 + g) ^ (r & 7)) * 8)];
      floatx4 ar = mfma_bf16(br0, qf[0][0], z4);
      ar = mfma_bf16(br1, qf[0][1], ar);
      floatx4 af = mfma_bf16(bf0, qf[1][0], z4);
      af = mfma_bf16(bf1, qf[1][1], af);
#pragma unroll
      for (int i = 0; i < 4; ++i) {
        const float pr = __builtin_amdgcn_exp2f(ar[i]) * inv_[0];
        const float pf = __builtin_amdgcn_exp2f(af[i]) * inv_[1];
        pA[kt2][i] = (short)f32_to_bf16_rne(fmaxf(pr, pf));
      }
    }

    // V B-frags: B[k=key kt2*16+g*4+j][n=d=nt*16+r] from swizzled Vs (b64).
    s4pack vB[2][2][4];
#pragma unroll
    for (int s = 0; s < 2; ++s)
#pragma unroll
      for (int kt2 = 0; kt2 < 2; ++kt2)
#pragma unroll
        for (int nt = 0; nt < 4; ++nt) {
          const int row = nt * 16 + r;
          const int cch = 2 * kt2 + (g >> 1);          // key chunk (of 8)
          const int addr =
              row * KVB + ((cch ^ ((r >> 2) & 3)) * 8) + (g & 1) * 4;
          vB[s][kt2][nt] = *(const s4pack*)&Vs[s][addr];
        }

    asm volatile("s_nop 7" :::);         // VALU(pA)->MFMA-read hazard guard
#pragma unroll
    for (int s = 0; s < 2; ++s)
#pragma unroll
      for (int nt = 0; nt < 4; ++nt) {
        mfma16(o_[s][nt], pA[0], vB[s][0][nt]);
        mfma16(o_[s][nt], pA[1], vB[s][1][nt]);
      }
  }

  // asm MFMA (o_) -> VALU/store read: explicit wait states (latency invisible
  // to the compiler's hazard pass).
  asm volatile("s_nop 7\n\ts_nop 7" :::);

  // write O: [B,S,512] bf16. lane holds O[q = g*4+i][d = nt*16+r]
  // (same epilogue mapping as R3).
  const int bb = bh >> 3, h = bh & 7;
#pragma unroll
  for (int s = 0; s < 2; ++s) {
    u16* out = p.O[s];
#pragma unroll
    for (int nt = 0; nt < 4; ++nt) {
      const int col = h * 64 + nt * 16 + r;
#pragma unroll
      for (int i = 0; i < 4; ++i) {
        const int row = q0 + wid * 16 + g * 4 + i;
        out[((size_t)bb * S_DIM + row) * DMODEL + col] =
            f32_to_bf16_rne(o_[s][nt][i]);
      }
    }
  }
}

// ---------------------------------------------------------------------------
// Kernel 3: output projections. 1-D grid = 512, XCD-chunked, m-major.
// ---------------------------------------------------------------------------
struct OutParams {
  const u16* A[2];
  const u16* W[2];
  const u16* Bias[2];
  float* Out[2];
};

__global__ __launch_bounds__(256) void out_gemm(OutParams p) {
  __shared__ u16 ldsA[3 * 128 * 32];
  __shared__ u16 ldsB[3 * 128 * 32];
  const int lin = blockIdx.x;
  const int wg = (lin & 7) * 64 + (lin >> 3);   // bijective (512 = 8*64)
  const int m0 = (wg >> 3) * 128;
  const int c = wg & 7;
  const int z = c >> 2;
  const int n0 = (c & 3) * 128;

  floatx4 acc[4][4];
  const floatx4 z4 = {0.f, 0.f, 0.f, 0.f};
#pragma unroll
  for (int i = 0; i < 4; ++i)
#pragma unroll
    for (int j = 0; j < 4; ++j) acc[i][j] = z4;

  gemm128_mainloop(p.A[z], p.W[z], m0, n0, ldsA, ldsB, acc);

  const int tid = threadIdx.x, lane = tid & 63, wid = tid >> 6;
  const int wm = wid >> 1, wn = wid & 1, r = lane & 15, g = lane >> 4;
  const u16* bias = p.Bias[z];
  float* out = p.Out[z];

#pragma unroll
  for (int j = 0; j < 4; ++j) {
    const int cc = n0 + wn * 64 + j * 16 + r;
    const float bv = bf16_bits_to_f32(bias[cc]);
#pragma unroll
    for (int i = 0; i < 4; ++i) {
      const int row0 = m0 + wm * 64 + i * 16 + g * 4;
#pragma unroll
      for (int ii = 0; ii < 4; ++ii)
        out[(size_t)(row0 + ii) * DMODEL + cc] = acc[i][j][ii] + bv;   // FP32
    }
  }
}

// ---------------------------------------------------------------------------
extern "C" void kernel_launch(void* const* d_in, const int* in_sizes, int n_in,
                              void* d_out, int out_size, void* d_ws, size_t ws_size,
                              hipStream_t stream) {
  (void)in_sizes; (void)n_in; (void)out_size; (void)ws_size;
  u16* ws = (u16*)d_ws;
  u16* Qr = ws + 0 * SEG;
  u16* Kr = ws + 1 * SEG;
  u16* Vr = ws + 2 * SEG;   // stored transposed [B,H,64,S]
  u16* Qf = ws + 3 * SEG;
  u16* Kf = ws + 4 * SEG;
  u16* Vf = ws + 5 * SEG;   // stored transposed [B,H,64,S]
  u16* Or = ws + 6 * SEG;   // also holds converted X_rgb before attn overwrites
  u16* Of = ws + 7 * SEG;   // also holds converted X_flow
  u16* cW = ws + 8 * SEG;            // 8 x 262144
  u16* cB = cW + 8 * WSEG;           // 8 x 512

  // ---- conversion pre-pass ----
  ConvParams cp;
  int coff = 0;
  for (int i = 0; i < NT_CONV; ++i) {
    cp.src[i] = d_in[i];
    int n;
    if (i < 2) {
      n = (int)SEG;
      cp.dst[i] = (i == 0) ? Or : Of;
    } else {
      const int k = (i - 2) >> 1;
      const int isb = (i - 2) & 1;
      n = isb ? DMODEL : (int)WSEG;
      cp.dst[i] = isb ? (cB + k * DMODEL) : (cW + k * WSEG);
    }
    cp.n[i] = n;
    cp.coff[i] = coff;
    coff += (n + 65535) / 65536;
  }
  cp.coff[NT_CONV] = coff;   // 168 chunks total
  convert_inputs<<<dim3(coff), dim3(256), 0, stream>>>(cp);

  // ---- QKV projections ----
  QkvParams qp;
  qp.X[0] = Or;
  qp.X[1] = Of;
  for (int s = 0; s < 2; ++s)
    for (int wi = 0; wi < 3; ++wi) {
      const int k = s * 3 + wi;
      qp.W[s][wi] = cW + k * WSEG;
      qp.Bias[s][wi] = cB + k * DMODEL;
    }
  qp.Out[0][0] = Qr; qp.Out[0][1] = Kr; qp.Out[0][2] = Vr;
  qp.Out[1][0] = Qf; qp.Out[1][1] = Kf; qp.Out[1][2] = Vf;
  qkv_gemm<<<dim3(1536), dim3(256), 0, stream>>>(qp);

  // ---- merged attention (overwrites Or/Of with O) ----
  AttnParams ap;
  ap.Q[0] = Qr; ap.Q[1] = Qf;
  ap.K[0] = Kr; ap.K[1] = Kf;
  ap.Vt[0] = Vr; ap.Vt[1] = Vf;
  ap.O[0] = Or; ap.O[1] = Of;
  attn_merged<<<dim3(1024), dim3(256), 0, stream>>>(ap);

  // ---- output projections (fp32 out) ----
  OutParams op;
  op.A[0] = Or; op.A[1] = Of;
  op.W[0] = cW + 6 * WSEG; op.Bias[0] = cB + 6 * DMODEL;
  op.W[1] = cW + 7 * WSEG; op.Bias[1] = cB + 7 * DMODEL;
  op.Out[0] = (float*)d_out;
  op.Out[1] = (float*)d_out + SEG;
  out_gemm<<<dim3(512), dim3(256), 0, stream>>>(op);
}

// Round 8
// 232.417 us; speedup vs baseline: 2.0410x; 1.2252x over previous
//
#include <hip/hip_runtime.h>
#include <hip/hip_bf16.h>

// MultiHeadedAttention2: dual-stream MHA with elementwise-max merge of the two
// softmax attention maps. Inputs fp32 (detected & converted to bf16 in ws);
// internal compute bf16 MFMA; OUTPUT WRITTEN AS FP32 (reference output dtype).
//
// Pipeline (4 dispatches):
//  0) convert_inputs: dtype-probe + convert/copy to bf16 in ws. 8192-elem
//     chunks -> grid 1288 (R7's 168-block grid was latency-bound).
//  1) qkv_gemm : 6 projections. Q,K -> [B,H,S,64] bf16, V -> [B,H,64,S] bf16.
//                XCD-chunked 1-D grid; 3-buffer counted-vmcnt mainloop.
//  2) attn_merged v5: QB=128, 2 q-subtiles per wave. The staged K/V tile
//                serves 2x the q rows; K/V fragments are read once into regs
//                and reused for both subtiles -> LDS cycles per q HALVE
//                (R3/R7 were LDS-pipe-bound: ~20 b128-ops x 12cyc x waves).
//                Swapped QK with PERMUTED K rows (rowA(r)=(r>>2)*8+(r&3), +4)
//                packs P in-lane as a 16x16x32 A-fragment -> PV uses the
//                plain mfma intrinsic (no asm), vB b128 shared across mt.
//  3) out_gemm : output projections + bias -> d_out (FP32), XCD-chunked grid.

typedef unsigned short u16;
typedef __attribute__((ext_vector_type(8))) short short8;   // 8 x bf16 (4 VGPRs)
typedef __attribute__((ext_vector_type(4))) short s4pack;   // 4 x bf16 (8 B)
typedef __attribute__((ext_vector_type(4))) float floatx4;  // MFMA accumulator

#define B_DIM 8
#define S_DIM 1024
#define H_DIM 8
#define DK 64
#define DMODEL 512
#define NTOK (B_DIM * S_DIM)                 // 8192 tokens
#define SEG ((size_t)NTOK * DMODEL)          // 4194304 elems per tensor
#define WSEG ((size_t)DMODEL * DMODEL)       // 262144 elems per weight

#define SCHED_FENCE() __builtin_amdgcn_sched_barrier(0)
#define LGKM0() asm volatile("s_waitcnt lgkmcnt(0)" ::: "memory")
#define BARRIER() __builtin_amdgcn_s_barrier()

__device__ __forceinline__ floatx4 mfma_bf16(short8 a, short8 b, floatx4 c) {
  return __builtin_amdgcn_mfma_f32_16x16x32_bf16(a, b, c, 0, 0, 0);
}

__device__ __forceinline__ u16 f32_to_bf16_rne(float f) {
  unsigned u = __float_as_uint(f);
  unsigned r = u + 0x7FFFu + ((u >> 16) & 1u);
  return (u16)(r >> 16);
}

__device__ __forceinline__ float bf16_bits_to_f32(u16 u) {
  return __uint_as_float(((unsigned)u) << 16);
}

// async global->LDS, 16B per lane; lds is the wave-uniform base
// (HW deposits lane i at lds + i*16).
__device__ __forceinline__ void async_cp16(const u16* g, u16* lds) {
  __builtin_amdgcn_global_load_lds(
      (__attribute__((address_space(1))) void*)(const_cast<u16*>(g)),
      (__attribute__((address_space(3))) void*)(lds), 16, 0, 0);
}

// ---------------------------------------------------------------------------
// Kernel 0: dtype-detect + convert to bf16. 8192-elem chunks, 4 iters each.
// ---------------------------------------------------------------------------
#define NT_CONV 18
#define CCHUNK 8192
struct ConvParams {
  const void* src[NT_CONV];
  u16* dst[NT_CONV];
  int n[NT_CONV];
  int coff[NT_CONV + 1];   // prefix sums of chunk counts
};

__global__ __launch_bounds__(256) void convert_inputs(ConvParams p) {
  __shared__ int flag_f32;
  const int blk = blockIdx.x;
  int t = 0;
  while (t + 1 < NT_CONV && blk >= p.coff[t + 1]) ++t;
  const int lc = blk - p.coff[t];
  const int n = p.n[t];
  const int tid = threadIdx.x;

  if (tid < 64) {
    const u16* s = (const u16*)p.src[t];
    int bad = 0;
#pragma unroll
    for (int j = 0; j < 8; ++j) {
      float f = bf16_bits_to_f32(s[tid * 8 + j]);
      bad |= !(fabsf(f) < 1e4f);   // catches huge AND NaN
    }
    bad |= __shfl_xor(bad, 1);
    bad |= __shfl_xor(bad, 2);
    bad |= __shfl_xor(bad, 4);
    bad |= __shfl_xor(bad, 8);
    bad |= __shfl_xor(bad, 16);
    bad |= __shfl_xor(bad, 32);
    if (tid == 0) flag_f32 = bad;
  }
  __syncthreads();
  const int is_f32 = flag_f32;
  const int base = lc * CCHUNK;

#pragma unroll
  for (int it = 0; it < CCHUNK / 2048; ++it) {
    const int idx = base + (it * 256 + tid) * 8;
    if (idx + 8 > n) break;
    if (!is_f32) {
      *(short8*)&p.dst[t][idx] = *(const short8*)&((const u16*)p.src[t])[idx];
    } else {
      const float* s = (const float*)p.src[t] + idx;
      short8 o;
#pragma unroll
      for (int j = 0; j < 8; ++j) o[j] = (short)f32_to_bf16_rne(s[j]);
      *(short8*)&p.dst[t][idx] = o;
    }
  }
}

// ---------------------------------------------------------------------------
// 128x128 NT GEMM mainloop, 3-buffer counted-vmcnt pipeline (T4).
// ---------------------------------------------------------------------------
__device__ __forceinline__ void gemm128_mainloop(
    const u16* __restrict__ A, const u16* __restrict__ W,
    int m0, int n0, u16* ldsA, u16* ldsB, floatx4 acc[4][4]) {
  const int tid = threadIdx.x;
  const int lane = tid & 63;
  const int wid = tid >> 6;
  const int wm = wid >> 1, wn = wid & 1;
  const int r = lane & 15, g = lane >> 4;

  const int stg_row = wid * 32 + (lane >> 2);
  const int stg_col = (lane & 3) * 8;

  const u16* ga0 = A + (size_t)(m0 + stg_row) * DMODEL + stg_col;
  const u16* ga1 = A + (size_t)(m0 + stg_row + 16) * DMODEL + stg_col;
  const u16* gb0 = W + (size_t)(n0 + stg_row) * DMODEL + stg_col;
  const u16* gb1 = W + (size_t)(n0 + stg_row + 16) * DMODEL + stg_col;
  const int lo0 = (wid * 32) * 32;        // wave-uniform LDS offsets
  const int lo1 = (wid * 32 + 16) * 32;

  // prologue: tiles 0..2 -> bufs 0..2 (12 loads/wave in flight)
#pragma unroll
  for (int t = 0; t < 3; ++t) {
    const int nb = t * 4096;
    const int ko = t * 32;
    async_cp16(ga0 + ko, ldsA + nb + lo0);
    async_cp16(ga1 + ko, ldsA + nb + lo1);
    async_cp16(gb0 + ko, ldsB + nb + lo0);
    async_cp16(gb1 + ko, ldsB + nb + lo1);
  }

#pragma unroll
  for (int kt = 0; kt < 16; ++kt) {
    SCHED_FENCE();
    if (kt < 14)       asm volatile("s_waitcnt vmcnt(8)" ::: "memory");
    else if (kt == 14) asm volatile("s_waitcnt vmcnt(4)" ::: "memory");
    else               asm volatile("s_waitcnt vmcnt(0)" ::: "memory");
    BARRIER();
    SCHED_FENCE();

    const int cb = (kt % 3) * 4096;
    short8 a[4], b[4];
#pragma unroll
    for (int i = 0; i < 4; ++i)
      a[i] = *(const short8*)&ldsA[cb + (wm * 64 + i * 16 + r) * 32 + g * 8];
#pragma unroll
    for (int j = 0; j < 4; ++j)
      b[j] = *(const short8*)&ldsB[cb + (wn * 64 + j * 16 + r) * 32 + g * 8];
#pragma unroll
    for (int i = 0; i < 4; ++i)
#pragma unroll
      for (int j = 0; j < 4; ++j)
        acc[i][j] = mfma_bf16(a[i], b[j], acc[i][j]);

    if (kt + 3 < 16) {
      SCHED_FENCE(); BARRIER(); SCHED_FENCE();
      const int ko = (kt + 3) * 32;
      async_cp16(ga0 + ko, ldsA + cb + lo0);
      async_cp16(ga1 + ko, ldsA + cb + lo1);
      async_cp16(gb0 + ko, ldsB + cb + lo0);
      async_cp16(gb1 + ko, ldsB + cb + lo1);
    }
  }
}

// ---------------------------------------------------------------------------
// Kernel 1: QKV projections. 1-D grid = 1536, XCD-chunked, m-major per chunk.
// ---------------------------------------------------------------------------
struct QkvParams {
  const u16* X[2];
  const u16* W[2][3];
  const u16* Bias[2][3];
  u16* Out[2][3];
};

__global__ __launch_bounds__(256) void qkv_gemm(QkvParams p) {
  __shared__ u16 ldsA[3 * 128 * 32];
  __shared__ u16 ldsB[3 * 128 * 32];
  const int lin = blockIdx.x;
  const int wg = (lin & 7) * 192 + (lin >> 3);   // bijective (1536 = 8*192)
  const int m0 = (wg / 24) * 128;
  const int c = wg % 24;
  const int z = c / 12;
  const int yc = c % 12;
  const int wi = yc >> 2;                        // 0=Q 1=K 2=V
  const int n0 = (yc & 3) * 128;

  floatx4 acc[4][4];
  const floatx4 z4 = {0.f, 0.f, 0.f, 0.f};
#pragma unroll
  for (int i = 0; i < 4; ++i)
#pragma unroll
    for (int j = 0; j < 4; ++j) acc[i][j] = z4;

  gemm128_mainloop(p.X[z], p.W[z][wi], m0, n0, ldsA, ldsB, acc);

  const int tid = threadIdx.x, lane = tid & 63, wid = tid >> 6;
  const int wm = wid >> 1, wn = wid & 1, r = lane & 15, g = lane >> 4;
  const u16* bias = p.Bias[z][wi];
  u16* out = p.Out[z][wi];
  const float qscale = 0.125f * 1.4426950408889634f;  // 1/sqrt(dk) * log2(e)

#pragma unroll
  for (int j = 0; j < 4; ++j) {
    const int cc = n0 + wn * 64 + j * 16 + r;         // output col in [0,512)
    const float bv = bf16_bits_to_f32(bias[cc]);
    const int h = cc >> 6, d = cc & 63;
#pragma unroll
    for (int i = 0; i < 4; ++i) {
      const int row0 = m0 + wm * 64 + i * 16 + g * 4; // 4 consecutive tokens
      const int bb = row0 >> 10, ss0 = row0 & 1023;
      if (wi == 2) {
        // V^T: [B,H,64,S]. 4 consecutive ss at fixed d -> one 8B store.
        s4pack pk;
#pragma unroll
        for (int ii = 0; ii < 4; ++ii)
          pk[ii] = (short)f32_to_bf16_rne(acc[i][j][ii] + bv);
        *(s4pack*)&out[(((size_t)(bb * H_DIM + h)) * DK + d) * S_DIM + ss0] = pk;
      } else {
#pragma unroll
        for (int ii = 0; ii < 4; ++ii) {
          float v = acc[i][j][ii] + bv;
          if (wi == 0) v *= qscale;                   // Q: pre-scaled
          out[(((size_t)(bb * H_DIM + h)) * S_DIM + (ss0 + ii)) * DK + d] =
              f32_to_bf16_rne(v);
        }
      }
    }
  }
}

// ---------------------------------------------------------------------------
// Kernel 2 v5: merged-softmax attention. grid = 512 (64 bh x 4 q-tiles of
// QB=128), XCD-chunked swizzle; whole grid resident (2 blocks/CU).
// Wave w owns q rows [q0 + w*32, +32) as two 16-row subtiles (mt=0,1).
//
// Per iter (KVB=32 keys): stage K/V once; read K-frags (permuted rows) and
// V-frags ONCE into registers; use them for BOTH q-subtiles -> LDS/q halves.
// Swapped QK with permuted K rows packs P[q=r][key g*8+0..7] in-lane =
// the 16x16x32 PV A-fragment.
// ---------------------------------------------------------------------------
#define KVB 32
#define QB 128

struct AttnParams {
  const u16* Q[2];
  const u16* K[2];
  const u16* Vt[2];
  u16* O[2];
};

__global__ __launch_bounds__(256, 2) void attn_merged(AttnParams p) {
  __shared__ u16 Ks[2][KVB * 64];   // [stream][key][d], chunk-swizzled (sK)
  __shared__ u16 Vs[2][64 * KVB];   // [stream][d][key], chunk-swizzled

  const int tid = threadIdx.x;
  const int lane = tid & 63;
  const int wid = tid >> 6;
  const int r = lane & 15, g = lane >> 4;

  // XCD-chunked bijective swizzle (512 = 8 XCD * 64): 8 whole heads per XCD.
  const int lin = blockIdx.x;
  const int w = (lin & 7) * 64 + (lin >> 3);
  const int bh = w >> 3;                 // (b*8+h)
  const int q0 = (w & 7) * QB;           // q-tile base
  const size_t hbase = (size_t)bh * S_DIM * DK;

  // K staging: thread -> (krow in [0,32), chunk kch in [0,8)); chunk slot
  // XOR-swizzled by sK(row) = (row&3)|(((row>>3)&1)<<2) so the PERMUTED
  // frag reads below hit all 8 chunk slots (row&7 would fold to 4).
  const int krow = tid >> 3, kch = tid & 7;
  const int sKr = (krow & 3) | (((krow >> 3) & 1) << 2);
  const int kdst = krow * 64 + ((kch ^ sKr) * 8);
  const size_t kgsrc = (size_t)krow * DK + kch * 8;
  // V staging: thread -> (vrow=d in [0,64), chunk vch in [0,4))
  const int vrow = tid >> 2, vch = tid & 3;
  const int vdst = vrow * KVB + ((vch ^ ((vrow >> 2) & 3)) * 8);
  const size_t vgsrc = (size_t)vrow * S_DIM + vch * 8;

  // Permuted K-frag addresses: A-half rows (r>>2)*8+(r&3) = keys 0-3,8-11,
  // 16-19,24-27; B-half = +4. Both halves share swizzle value srg.
  const int srg = (r & 3) | (((r >> 2) & 1) << 2);
  const int rowAo = ((r >> 2) * 8 + (r & 3)) * 64;   // u16 offset of A-row
  const int cA0 = (g ^ srg) * 8;                     // d-chunk g (d 0..31)
  const int cA1 = ((4 + g) ^ srg) * 8;               // d-chunk 4+g (d 32..63)

  // Q fragments (B-operand): lane holds Q[q=q0+wid*32+mt*16+r][d=kc*32+g*8+j]
  short8 qf[2][2][2];
#pragma unroll
  for (int s = 0; s < 2; ++s)
#pragma unroll
    for (int mt = 0; mt < 2; ++mt)
#pragma unroll
      for (int kc = 0; kc < 2; ++kc)
        qf[s][mt][kc] = *(const short8*)
            &p.Q[s][hbase + (size_t)(q0 + wid * 32 + mt * 16 + r) * DK +
                    kc * 32 + g * 8];

  // tile-0 K prefetch
  short8 kst[2], vst[2];
#pragma unroll
  for (int s = 0; s < 2; ++s)
    kst[s] = *(const short8*)&p.K[s][hbase + kgsrc];

  const floatx4 z4 = {0.f, 0.f, 0.f, 0.f};
  float sl[2][2] = {{0.f, 0.f}, {0.f, 0.f}};   // [s][mt] 2^score sums, q=r

  // ---- pass 1: per-q sums of 2^score for both streams ----
  for (int kt = 0; kt < 32; ++kt) {
    if (kt) { SCHED_FENCE(); BARRIER(); SCHED_FENCE(); }
#pragma unroll
    for (int s = 0; s < 2; ++s)       // implicit counted vmcnt on kst only
      *(short8*)&Ks[s][kdst] = kst[s];
    if (kt < 31) {
      const size_t k0n = (size_t)(kt + 1) * KVB * DK;
#pragma unroll
      for (int s = 0; s < 2; ++s)
        kst[s] = *(const short8*)&p.K[s][hbase + k0n + kgsrc];
    }
    SCHED_FENCE(); LGKM0(); BARRIER(); SCHED_FENCE();

#pragma unroll
    for (int s = 0; s < 2; ++s) {
      const short8 kA0 = *(const short8*)&Ks[s][rowAo + cA0];
      const short8 kA1 = *(const short8*)&Ks[s][rowAo + cA1];
      const short8 kB0 = *(const short8*)&Ks[s][rowAo + 256 + cA0];
      const short8 kB1 = *(const short8*)&Ks[s][rowAo + 256 + cA1];
#pragma unroll
      for (int mt = 0; mt < 2; ++mt) {
        floatx4 aA = mfma_bf16(kA0, qf[s][mt][0], z4);
        aA = mfma_bf16(kA1, qf[s][mt][1], aA);
        floatx4 aB = mfma_bf16(kB0, qf[s][mt][0], z4);
        aB = mfma_bf16(kB1, qf[s][mt][1], aB);
        sl[s][mt] += __builtin_amdgcn_exp2f(aA[0]) + __builtin_amdgcn_exp2f(aA[1]) +
                     __builtin_amdgcn_exp2f(aA[2]) + __builtin_amdgcn_exp2f(aA[3]) +
                     __builtin_amdgcn_exp2f(aB[0]) + __builtin_amdgcn_exp2f(aB[1]) +
                     __builtin_amdgcn_exp2f(aB[2]) + __builtin_amdgcn_exp2f(aB[3]);
      }
    }
  }

  // pass-2 tile-0 staged loads: issued now so they fly under the reduction
#pragma unroll
  for (int s = 0; s < 2; ++s) {
    kst[s] = *(const short8*)&p.K[s][hbase + kgsrc];
    vst[s] = *(const short8*)&p.Vt[s][hbase + vgsrc];
  }

  // reduce over g (key groups); lane keeps the total for its q=r.
  float inv_[2][2];
#pragma unroll
  for (int s = 0; s < 2; ++s)
#pragma unroll
    for (int mt = 0; mt < 2; ++mt) {
      float v = sl[s][mt];
      v += __shfl_xor(v, 16);
      v += __shfl_xor(v, 32);
      inv_[s][mt] = 1.0f / v;
    }

  floatx4 o_[2][2][4];   // [s][mt][nt(d)] : lane holds O[q=mt*16+g*4+i][d=nt*16+r]
#pragma unroll
  for (int s = 0; s < 2; ++s)
#pragma unroll
    for (int mt = 0; mt < 2; ++mt)
#pragma unroll
      for (int nt = 0; nt < 4; ++nt) o_[s][mt][nt] = z4;

  // ---- pass 2: recompute scores, p = max(softmax_r, softmax_f), O += P@V ----
  for (int kt = 0; kt < 32; ++kt) {
    // kt==0 barrier also closes pass-1's last readers of Ks
    SCHED_FENCE(); BARRIER(); SCHED_FENCE();
#pragma unroll
    for (int s = 0; s < 2; ++s) {
      *(short8*)&Ks[s][kdst] = kst[s];
      *(short8*)&Vs[s][vdst] = vst[s];
    }
    if (kt < 31) {
      const size_t kn = (size_t)(kt + 1) * KVB;
#pragma unroll
      for (int s = 0; s < 2; ++s) {
        kst[s] = *(const short8*)&p.K[s][hbase + kn * DK + kgsrc];
        vst[s] = *(const short8*)&p.Vt[s][hbase + vgsrc + kn];
      }
    }
    SCHED_FENCE(); LGKM0(); BARRIER(); SCHED_FENCE();

    // K-frags once (permuted rows), reused for both q-subtiles.
    short8 kA0[2], kA1[2], kB0[2], kB1[2];
#pragma unroll
    for (int s = 0; s < 2; ++s) {
      kA0[s] = *(const short8*)&Ks[s][rowAo + cA0];
      kA1[s] = *(const short8*)&Ks[s][rowAo + cA1];
      kB0[s] = *(const short8*)&Ks[s][rowAo + 256 + cA0];
      kB1[s] = *(const short8*)&Ks[s][rowAo + 256 + cA1];
    }

    // QK (swapped, permuted) + merged softmax -> packed PV A-frag per mt:
    // pA[mt] holds P[q=r][key = g*8 + j], j=0..7.
    short8 pA[2];
#pragma unroll
    for (int mt = 0; mt < 2; ++mt) {
      floatx4 arA = mfma_bf16(kA0[0], qf[0][mt][0], z4);
      arA = mfma_bf16(kA1[0], qf[0][mt][1], arA);
      floatx4 arB = mfma_bf16(kB0[0], qf[0][mt][0], z4);
      arB = mfma_bf16(kB1[0], qf[0][mt][1], arB);
      floatx4 afA = mfma_bf16(kA0[1], qf[1][mt][0], z4);
      afA = mfma_bf16(kA1[1], qf[1][mt][1], afA);
      floatx4 afB = mfma_bf16(kB0[1], qf[1][mt][0], z4);
      afB = mfma_bf16(kB1[1], qf[1][mt][1], afB);
#pragma unroll
      for (int i = 0; i < 4; ++i) {
        const float prA = __builtin_amdgcn_exp2f(arA[i]) * inv_[0][mt];
        const float pfA = __builtin_amdgcn_exp2f(afA[i]) * inv_[1][mt];
        pA[mt][i] = (short)f32_to_bf16_rne(fmaxf(prA, pfA));
        const float prB = __builtin_amdgcn_exp2f(arB[i]) * inv_[0][mt];
        const float pfB = __builtin_amdgcn_exp2f(afB[i]) * inv_[1][mt];
        pA[mt][4 + i] = (short)f32_to_bf16_rne(fmaxf(prB, pfB));
      }
    }

    // V B-frags once (b128), reused for both q-subtiles:
    // B[k=key g*8+j][n=d=r] = Vs[d-row nt*16+r][key-chunk g].
    short8 vB[2][4];
#pragma unroll
    for (int s = 0; s < 2; ++s)
#pragma unroll
      for (int nt = 0; nt < 4; ++nt)
        vB[s][nt] = *(const short8*)
            &Vs[s][(nt * 16 + r) * KVB + ((g ^ ((r >> 2) & 3)) * 8)];

#pragma unroll
    for (int s = 0; s < 2; ++s)
#pragma unroll
      for (int mt = 0; mt < 2; ++mt)
#pragma unroll
        for (int nt = 0; nt < 4; ++nt)
          o_[s][mt][nt] = mfma_bf16(pA[mt], vB[s][nt], o_[s][mt][nt]);
  }

  // write O: [B,S,512] bf16. lane holds O[q = mt*16+g*4+i][d = nt*16+r].
  const int bb = bh >> 3, h = bh & 7;
#pragma unroll
  for (int s = 0; s < 2; ++s) {
    u16* out = p.O[s];
#pragma unroll
    for (int mt = 0; mt < 2; ++mt)
#pragma unroll
      for (int nt = 0; nt < 4; ++nt) {
        const int col = h * 64 + nt * 16 + r;
#pragma unroll
        for (int i = 0; i < 4; ++i) {
          const int row = q0 + wid * 32 + mt * 16 + g * 4 + i;
          out[((size_t)bb * S_DIM + row) * DMODEL + col] =
              f32_to_bf16_rne(o_[s][mt][nt][i]);
        }
      }
  }
}

// ---------------------------------------------------------------------------
// Kernel 3: output projections. 1-D grid = 512, XCD-chunked, m-major.
// ---------------------------------------------------------------------------
struct OutParams {
  const u16* A[2];
  const u16* W[2];
  const u16* Bias[2];
  float* Out[2];
};

__global__ __launch_bounds__(256) void out_gemm(OutParams p) {
  __shared__ u16 ldsA[3 * 128 * 32];
  __shared__ u16 ldsB[3 * 128 * 32];
  const int lin = blockIdx.x;
  const int wg = (lin & 7) * 64 + (lin >> 3);   // bijective (512 = 8*64)
  const int m0 = (wg >> 3) * 128;
  const int c = wg & 7;
  const int z = c >> 2;
  const int n0 = (c & 3) * 128;

  floatx4 acc[4][4];
  const floatx4 z4 = {0.f, 0.f, 0.f, 0.f};
#pragma unroll
  for (int i = 0; i < 4; ++i)
#pragma unroll
    for (int j = 0; j < 4; ++j) acc[i][j] = z4;

  gemm128_mainloop(p.A[z], p.W[z], m0, n0, ldsA, ldsB, acc);

  const int tid = threadIdx.x, lane = tid & 63, wid = tid >> 6;
  const int wm = wid >> 1, wn = wid & 1, r = lane & 15, g = lane >> 4;
  const u16* bias = p.Bias[z];
  float* out = p.Out[z];

#pragma unroll
  for (int j = 0; j < 4; ++j) {
    const int cc = n0 + wn * 64 + j * 16 + r;
    const float bv = bf16_bits_to_f32(bias[cc]);
#pragma unroll
    for (int i = 0; i < 4; ++i) {
      const int row0 = m0 + wm * 64 + i * 16 + g * 4;
#pragma unroll
      for (int ii = 0; ii < 4; ++ii)
        out[(size_t)(row0 + ii) * DMODEL + cc] = acc[i][j][ii] + bv;   // FP32
    }
  }
}

// ---------------------------------------------------------------------------
extern "C" void kernel_launch(void* const* d_in, const int* in_sizes, int n_in,
                              void* d_out, int out_size, void* d_ws, size_t ws_size,
                              hipStream_t stream) {
  (void)in_sizes; (void)n_in; (void)out_size; (void)ws_size;
  u16* ws = (u16*)d_ws;
  u16* Qr = ws + 0 * SEG;
  u16* Kr = ws + 1 * SEG;
  u16* Vr = ws + 2 * SEG;   // stored transposed [B,H,64,S]
  u16* Qf = ws + 3 * SEG;
  u16* Kf = ws + 4 * SEG;
  u16* Vf = ws + 5 * SEG;   // stored transposed [B,H,64,S]
  u16* Or = ws + 6 * SEG;   // also holds converted X_rgb before attn overwrites
  u16* Of = ws + 7 * SEG;   // also holds converted X_flow
  u16* cW = ws + 8 * SEG;            // 8 x 262144
  u16* cB = cW + 8 * WSEG;           // 8 x 512

  // ---- conversion pre-pass ----
  ConvParams cp;
  int coff = 0;
  for (int i = 0; i < NT_CONV; ++i) {
    cp.src[i] = d_in[i];
    int n;
    if (i < 2) {
      n = (int)SEG;
      cp.dst[i] = (i == 0) ? Or : Of;
    } else {
      const int k = (i - 2) >> 1;
      const int isb = (i - 2) & 1;
      n = isb ? DMODEL : (int)WSEG;
      cp.dst[i] = isb ? (cB + k * DMODEL) : (cW + k * WSEG);
    }
    cp.n[i] = n;
    cp.coff[i] = coff;
    coff += (n + CCHUNK - 1) / CCHUNK;
  }
  cp.coff[NT_CONV] = coff;   // 1288 chunks total
  convert_inputs<<<dim3(coff), dim3(256), 0, stream>>>(cp);

  // ---- QKV projections ----
  QkvParams qp;
  qp.X[0] = Or;
  qp.X[1] = Of;
  for (int s = 0; s < 2; ++s)
    for (int wi = 0; wi < 3; ++wi) {
      const int k = s * 3 + wi;
      qp.W[s][wi] = cW + k * WSEG;
      qp.Bias[s][wi] = cB + k * DMODEL;
    }
  qp.Out[0][0] = Qr; qp.Out[0][1] = Kr; qp.Out[0][2] = Vr;
  qp.Out[1][0] = Qf; qp.Out[1][1] = Kf; qp.Out[1][2] = Vf;
  qkv_gemm<<<dim3(1536), dim3(256), 0, stream>>>(qp);

  // ---- merged attention (overwrites Or/Of with O) ----
  AttnParams ap;
  ap.Q[0] = Qr; ap.Q[1] = Qf;
  ap.K[0] = Kr; ap.K[1] = Kf;
  ap.Vt[0] = Vr; ap.Vt[1] = Vf;
  ap.O[0] = Or; ap.O[1] = Of;
  attn_merged<<<dim3(512), dim3(256), 0, stream>>>(ap);

  // ---- output projections (fp32 out) ----
  OutParams op;
  op.A[0] = Or; op.A[1] = Of;
  op.W[0] = cW + 6 * WSEG; op.Bias[0] = cB + 6 * DMODEL;
  op.W[1] = cW + 7 * WSEG; op.Bias[1] = cB + 7 * DMODEL;
  op.Out[0] = (float*)d_out;
  op.Out[1] = (float*)d_out + SEG;
  out_gemm<<<dim3(512), dim3(256), 0, stream>>>(op);
}